// Round 11
// baseline (180.870 us; speedup 1.0000x reference)
//
#include <hip/hip_runtime.h>
#include <hip/hip_bf16.h>

#define S_LEN   2048
#define D_DIM   64
#define BK      64
#define NBH     32

typedef __attribute__((ext_vector_type(8))) short  short8;
typedef __attribute__((ext_vector_type(4))) float  floatx4;

#define KLD   72   // prep V-transpose LDS pitch
#define PLD   72   // P tiles per wave: 2 x [16 q][72] bf16
#define OLD   65   // epilogue fp32 transpose pitch
#define SMEM_BYTES 18432   // 4 waves * 32*72*2 (P only; no K/V staging)

// flat split-K: 40 (qi,part) slots per bh, KCHUNK=8 K-tiles max per part
__constant__ int c_slot_qi[40] = {15,15,15,15,14,14,14,13,13,13,12,12,12,11,11,11,10,10,9,9,8,8,7,7,6,5,4,3, 14,10,6,2, 13,9,5,1, 12,8,4,0};
__constant__ int c_slot_p [40] = { 0, 1, 2, 3, 0, 1, 2, 0, 1, 2, 0, 1, 2, 0, 1, 2, 0, 1,0,1,0,1,0,1,0,0,0,0,  3, 2,1,0,  3,2,1,0,  3,2,1,0};
__constant__ int c_pfx[16] = {0,1,2,3,4,6,8,10,12,15,18,21,24,28,32,36};
__constant__ int c_np [16] = {1,1,1,1,2,2,2,2,3,3,3,3,4,4,4,4};

__device__ __forceinline__ unsigned pk2(float lo, float hi) {
  __hip_bfloat162 h = __float22bfloat162_rn(float2{lo, hi});  // v_cvt_pk_bf16_f32
  union { __hip_bfloat162 v; unsigned u; } c; c.v = h;
  return c.u;
}
__device__ __forceinline__ short8 pk8(const float* f) {
  union { short8 s; unsigned u[4]; } r;
  r.u[0] = pk2(f[0], f[1]); r.u[1] = pk2(f[2], f[3]);
  r.u[2] = pk2(f[4], f[5]); r.u[3] = pk2(f[6], f[7]);
  return r.s;
}
__device__ __forceinline__ float bf2f(unsigned short s) {
  union { unsigned u; float f; } c; c.u = ((unsigned)s) << 16; return c.f;
}

// ---- prep: K fp32 -> bf16 [bh][s][d]; V fp32 -> bf16 V^T [bh][d][s] ----
__global__ __launch_bounds__(256, 2)
void prep(const float* __restrict__ K, const float* __restrict__ V,
          unsigned short* __restrict__ Kbf, unsigned short* __restrict__ Vt)
{
  __shared__ unsigned short vt[64 * KLD];
  const int tid = threadIdx.x;
  const int bh  = blockIdx.x >> 5;
  const int k0  = (blockIdx.x & 31) * 64;

  {
    const int k   = k0 + (tid >> 2);
    const int seg = (tid & 3) * 16;
    const float* p = K + ((size_t)(bh * S_LEN + k)) * D_DIM + seg;
    union { float4 v[4]; float f[16]; } u;
    u.v[0] = *(const float4*)p;       u.v[1] = *(const float4*)(p + 4);
    u.v[2] = *(const float4*)(p + 8); u.v[3] = *(const float4*)(p + 12);
    unsigned short* dst = Kbf + ((size_t)(bh * S_LEN + k)) * D_DIM + seg;
    *(short8*)dst       = pk8(u.f);
    *(short8*)(dst + 8) = pk8(u.f + 8);
  }
  {
    const int kp2 = tid & 31;
    const int dg  = (tid >> 5) * 8;
    const float* p = V + ((size_t)(bh * S_LEN + k0 + 2 * kp2)) * D_DIM + dg;
    union { float4 v[2]; float f[8]; } x, y;
    x.v[0] = *(const float4*)p;            x.v[1] = *(const float4*)(p + 4);
    y.v[0] = *(const float4*)(p + D_DIM);  y.v[1] = *(const float4*)(p + D_DIM + 4);
#pragma unroll
    for (int i = 0; i < 8; ++i)
      *(unsigned*)&vt[(dg + i) * KLD + 2 * kp2] = pk2(x.f[i], y.f[i]);
  }
  __syncthreads();
  {
    const int d   = tid >> 2;
    const int seg = (tid & 3) * 16;
    short8 a = *(short8*)&vt[d * KLD + seg];
    short8 b = *(short8*)&vt[d * KLD + seg + 8];
    unsigned short* dst = Vt + ((size_t)(bh * D_DIM + d)) * S_LEN + k0 + seg;
    *(short8*)dst       = a;
    *(short8*)(dst + 8) = b;
  }
}

// Barrier-free FA: MFMA fragments loaded directly from global (L1/L2-resident
// bf16 K / V^T), no K/V LDS staging, no __syncthreads in the K-loop. LDS holds
// only the per-wave P round-trip. Fixed-base softmax; flat split-K + merge.
__global__ __launch_bounds__(256, 2)
void fa_fwd(const float* __restrict__ Qg,
            const unsigned short* __restrict__ Kbf,
            const unsigned short* __restrict__ Vt,
            float* __restrict__ Og,
            unsigned short* __restrict__ Opart,
            float* __restrict__ Lpart)
{
  __shared__ char smem[SMEM_BYTES];

  const int tid  = threadIdx.x;
  const int wv   = tid >> 6;
  const int lane = tid & 63;
  const int col  = lane & 15;
  const int quad = lane >> 4;
  short* PA = (short*)smem + wv * (32 * PLD);
  short* PB = PA + 16 * PLD;
  float* Olds = (float*)PA;            // epilogue alias of this wave's P region

  const int slot = blockIdx.x >> 5;    // big parts first; same-bh stride 32 -> same XCD
  const int bh   = blockIdx.x & 31;
  const int qi   = c_slot_qi[slot];
  const int part = c_slot_p[slot];
  const int nk   = 2 * (qi + 1);
  const int it0  = part * 8;
  const int itend = (it0 + 8 < nk) ? it0 + 8 : nk;
  const bool multi = (c_np[qi] > 1);
  const int q0 = qi * 128;

  const float qscale = 0.18033688011112042f;   // log2(e)/sqrt(64)
  const float*          Qb  = Qg  + (size_t)bh * S_LEN * D_DIM;
  const unsigned short* Kb  = Kbf + (size_t)bh * S_LEN * D_DIM;
  const unsigned short* Vtb = Vt  + (size_t)bh * D_DIM * S_LEN;
  float*                Ob  = Og  + (size_t)bh * S_LEN * D_DIM;

  const int qws[2] = {q0 + wv * 16, q0 + 64 + wv * 16};

  // ---- Q fragments for both 16-q tiles ----
  short8 qf[2][2];
#pragma unroll
  for (int qt = 0; qt < 2; ++qt)
#pragma unroll
    for (int h = 0; h < 2; ++h) {
      const float* qp = Qb + (size_t)(qws[qt] + col) * D_DIM + h * 32 + quad * 8;
      union { float4 v[2]; float f[8]; } u;
      u.v[0] = *(const float4*)qp; u.v[1] = *(const float4*)(qp + 4);
      float t[8];
#pragma unroll
      for (int j = 0; j < 8; ++j) t[j] = u.f[j] * qscale;
      qf[qt][h] = pk8(t);
    }

  floatx4 o[2][4];
#pragma unroll
  for (int qt = 0; qt < 2; ++qt)
#pragma unroll
    for (int dt = 0; dt < 4; ++dt) o[qt][dt] = (floatx4){0.f,0.f,0.f,0.f};
  float l_run[2] = {0.f, 0.f};

  for (int it = it0; it < itend; ++it) {
    const int  kb  = it * BK;
    const bool doA = (kb != q0 + 64);   // tile A fully masked on the final diagonal iter

    // ---- K fragments direct from global (16 x 64B lines per load, L1/L2) ----
    short8 kfr[4][2];
#pragma unroll
    for (int kt = 0; kt < 4; ++kt) {
      const unsigned short* kp = Kb + (size_t)(kb + kt * 16 + col) * D_DIM + quad * 8;
      kfr[kt][0] = *(const short8*)kp;
      kfr[kt][1] = *(const short8*)(kp + 32);
    }

    // ---- S^T = K · Q^T ----
    floatx4 st[2][4];
#pragma unroll
    for (int kt = 0; kt < 4; ++kt) {
      floatx4 c = (floatx4){0.f,0.f,0.f,0.f};
      c = __builtin_amdgcn_mfma_f32_16x16x32_bf16(kfr[kt][0], qf[1][0], c, 0, 0, 0);
      c = __builtin_amdgcn_mfma_f32_16x16x32_bf16(kfr[kt][1], qf[1][1], c, 0, 0, 0);
      st[1][kt] = c;
      if (doA) {
        floatx4 d = (floatx4){0.f,0.f,0.f,0.f};
        d = __builtin_amdgcn_mfma_f32_16x16x32_bf16(kfr[kt][0], qf[0][0], d, 0, 0, 0);
        d = __builtin_amdgcn_mfma_f32_16x16x32_bf16(kfr[kt][1], qf[0][1], d, 0, 0, 0);
        st[0][kt] = d;
      }
    }

    // ---- V^T fragments issued now; land during softmax ----
    short8 vfr[2][4];
#pragma unroll
    for (int g = 0; g < 2; ++g)
#pragma unroll
      for (int dt = 0; dt < 4; ++dt)
        vfr[g][dt] = *(const short8*)(Vtb + (size_t)(dt * 16 + col) * S_LEN + kb + g * 32 + quad * 8);

    // ---- causal masks: only near the diagonal ----
    if (kb == q0) {
      const int qg = qws[0] + col;
#pragma unroll
      for (int kt = 0; kt < 4; ++kt)
#pragma unroll
        for (int r = 0; r < 4; ++r)
          if (kb + kt * 16 + quad * 4 + r > qg) st[0][kt][r] = -3.0e38f;
    }
    if (!doA) {
      const int qg = qws[1] + col;
#pragma unroll
      for (int kt = 0; kt < 4; ++kt)
#pragma unroll
        for (int r = 0; r < 4; ++r)
          if (kb + kt * 16 + quad * 4 + r > qg) st[1][kt][r] = -3.0e38f;
    }

    // ---- fixed-base softmax + P -> per-wave LDS (no barrier) ----
#pragma unroll
    for (int qt = 0; qt < 2; ++qt) {
      if (qt == 0 && !doA) continue;
      float lsum = 0.f;
#pragma unroll
      for (int kt = 0; kt < 4; ++kt)
#pragma unroll
        for (int r = 0; r < 4; ++r) {
          const float p = __builtin_amdgcn_exp2f(st[qt][kt][r]);
          st[qt][kt][r] = p;
          lsum += p;
        }
      l_run[qt] += lsum;
      short* Pq = qt ? PB : PA;
#pragma unroll
      for (int kt = 0; kt < 4; ++kt) {
        uint2 w; w.x = pk2(st[qt][kt][0], st[qt][kt][1]); w.y = pk2(st[qt][kt][2], st[qt][kt][3]);
        *(uint2*)&Pq[col * PLD + kt * 16 + quad * 4] = w;
      }
    }

    // ---- O^T += V^T · P^T ----
#pragma unroll
    for (int g = 0; g < 2; ++g) {
      short8 pfB = *(short8*)&PB[col * PLD + g * 32 + quad * 8];
      short8 pfA;
      if (doA) pfA = *(short8*)&PA[col * PLD + g * 32 + quad * 8];
#pragma unroll
      for (int dt = 0; dt < 4; ++dt) {
        o[1][dt] = __builtin_amdgcn_mfma_f32_16x16x32_bf16(vfr[g][dt], pfB, o[1][dt], 0, 0, 0);
        if (doA)
          o[0][dt] = __builtin_amdgcn_mfma_f32_16x16x32_bf16(vfr[g][dt], pfA, o[0][dt], 0, 0, 0);
      }
    }
  }

  // ---- epilogue (per-wave LDS transpose; no block barrier needed) ----
#pragma unroll
  for (int qt = 0; qt < 2; ++qt) {
    float l = l_run[qt];
    l += __shfl_xor(l, 16);
    l += __shfl_xor(l, 32);
    if (!multi) {
      const float inv = 1.0f / l;
#pragma unroll
      for (int dt = 0; dt < 4; ++dt)
#pragma unroll
        for (int r = 0; r < 4; ++r)
          Olds[col * OLD + dt * 16 + quad * 4 + r] = o[qt][dt][r] * inv;
#pragma unroll
      for (int it2 = 0; it2 < 4; ++it2) {
        const int ql = it2 * 4 + quad;
        float4 w;
        w.x = Olds[ql * OLD + col * 4 + 0];
        w.y = Olds[ql * OLD + col * 4 + 1];
        w.z = Olds[ql * OLD + col * 4 + 2];
        w.w = Olds[ql * OLD + col * 4 + 3];
        *(float4*)(Ob + (size_t)(qws[qt] + ql) * D_DIM + col * 4) = w;
      }
    } else {
#pragma unroll
      for (int dt = 0; dt < 4; ++dt)
#pragma unroll
        for (int r = 0; r < 4; ++r)
          Olds[col * OLD + dt * 16 + quad * 4 + r] = o[qt][dt][r];
      const size_t prow = (size_t)bh * 5120 + (size_t)(c_pfx[qi] + part) * 128;
#pragma unroll
      for (int it2 = 0; it2 < 4; ++it2) {
        const int ql = it2 * 4 + quad;
        const int qlocal = qt * 64 + wv * 16 + ql;
        float4 w;
        w.x = Olds[ql * OLD + col * 4 + 0];
        w.y = Olds[ql * OLD + col * 4 + 1];
        w.z = Olds[ql * OLD + col * 4 + 2];
        w.w = Olds[ql * OLD + col * 4 + 3];
        uint2 pw; pw.x = pk2(w.x, w.y); pw.y = pk2(w.z, w.w);
        *(uint2*)&Opart[(prow + qlocal) * 64 + col * 4] = pw;
      }
      if (quad == 0)
        Lpart[prow + qt * 64 + wv * 16 + col] = l;
    }
  }
}

// ---- merge: O = sum_p(Opart) / sum_p(l) for qi >= 4 (np = 2..4) ----
__global__ __launch_bounds__(256, 2)
void merge(const unsigned short* __restrict__ Opart,
           const float* __restrict__ Lpart,
           float* __restrict__ Og)
{
  const int tid = threadIdx.x;
  const int gid = blockIdx.x * 64 + (tid >> 2);  // 0..49151: (bh, qi-4, ql)
  const int seg = (tid & 3) * 16;
  const int bh  = gid / 1536;
  const int rem = gid - bh * 1536;
  const int qi  = 4 + (rem >> 7);
  const int ql  = rem & 127;
  const int np  = c_np[qi];
  const size_t base = (size_t)bh * 5120 + (size_t)c_pfx[qi] * 128 + ql;

  float acc[16];
#pragma unroll
  for (int j = 0; j < 16; ++j) acc[j] = 0.f;
  float l = 0.f;
  for (int p = 0; p < np; ++p) {
    const size_t row = base + (size_t)p * 128;
    l += Lpart[row];
    const unsigned short* pp = Opart + row * 64 + seg;
    union { short8 s; unsigned short h[8]; } a0, a1;
    a0.s = *(short8*)pp; a1.s = *(short8*)(pp + 8);
#pragma unroll
    for (int j = 0; j < 8; ++j) acc[j]     += bf2f(a0.h[j]);
#pragma unroll
    for (int j = 0; j < 8; ++j) acc[8 + j] += bf2f(a1.h[j]);
  }
  const float inv = 1.0f / l;
  float* dst = Og + ((size_t)bh * S_LEN + qi * 128 + ql) * D_DIM + seg;
#pragma unroll
  for (int j = 0; j < 16; ++j) acc[j] *= inv;
#pragma unroll
  for (int j = 0; j < 4; ++j)
    *(float4*)(dst + 4 * j) = *(float4*)&acc[4 * j];
}

extern "C" void kernel_launch(void* const* d_in, const int* in_sizes, int n_in,
                              void* d_out, int out_size, void* d_ws, size_t ws_size,
                              hipStream_t stream) {
  const float* Q = (const float*)d_in[0];
  const float* K = (const float*)d_in[1];
  const float* V = (const float*)d_in[2];
  float* O = (float*)d_out;
  unsigned short* Kbf   = (unsigned short*)d_ws;                    // 8.4 MB
  unsigned short* Vt    = Kbf + (size_t)NBH * S_LEN * D_DIM;        // 8.4 MB
  unsigned short* Opart = Vt  + (size_t)NBH * S_LEN * D_DIM;        // 21.0 MB (32*5120 rows x 64 bf16)
  float*          Lpart = (float*)(Opart + (size_t)NBH * 5120 * 64); // 0.66 MB

  hipLaunchKernelGGL(prep,   dim3(NBH * (S_LEN / 64)), dim3(256), 0, stream, K, V, Kbf, Vt);
  hipLaunchKernelGGL(fa_fwd, dim3(40 * NBH), dim3(256), 0, stream, Q, Kbf, Vt, O, Opart, Lpart);
  hipLaunchKernelGGL(merge,  dim3(768), dim3(256), 0, stream, Opart, Lpart, O);
}